// Round 4
// baseline (12970.972 us; speedup 1.0000x reference)
//
#include <hip/hip_runtime.h>
#include <math.h>

// ---------------- problem constants ----------------
#define TS   2048   // timesteps
#define NN   100    // nodes
#define FD   128    // input features
#define HD   512    // hidden
#define G3   1536   // 3*HD
#define NG   7      // node groups of 16
#define NSL  8      // hidden slices (64 h-cols each)
#define KNN  8
#define GIN  704    // HD + 64 + 128
#define GH   256
#define GOUT 128

typedef float  f32x4  __attribute__((ext_vector_type(4)));
typedef __bf16 bf16x8 __attribute__((ext_vector_type(8)));
typedef unsigned long long u64;
#define MFMA16(a, b, c) __builtin_amdgcn_mfma_f32_16x16x32_bf16((a), (b), (c), 0, 0, 0)

#define WXST 136   // Wx/Ax LDS row stride (bf16): 272B, 16B-aligned
#define HNST 72    // Hn row stride

__device__ __forceinline__ float sigmoidf_(float v) { return 1.f / (1.f + __expf(-v)); }
__device__ __forceinline__ float tanhf_(float v) {
    float ex = __expf(2.f * v);
    return 1.f - 2.f / (ex + 1.f);
}

// coherent (LLC-routed) accesses: relaxed agent-scope atomics (bypass L1/L2).
__device__ __forceinline__ u64 cload(const u64* p) {
    return __hip_atomic_load(p, __ATOMIC_RELAXED, __HIP_MEMORY_SCOPE_AGENT);
}
__device__ __forceinline__ void cstore(u64* p, u64 v) {
    __hip_atomic_store(p, v, __ATOMIC_RELAXED, __HIP_MEMORY_SCOPE_AGENT);
}

__device__ __forceinline__ bf16x8 cvt8(const float* p) {
    float4 a = *(const float4*)p, b = *(const float4*)(p + 4);
    bf16x8 r;
    r[0] = (__bf16)a.x; r[1] = (__bf16)a.y; r[2] = (__bf16)a.z; r[3] = (__bf16)a.w;
    r[4] = (__bf16)b.x; r[5] = (__bf16)b.y; r[6] = (__bf16)b.z; r[7] = (__bf16)b.w;
    return r;
}

struct __align__(16) HQ { u64 a, b; };

// =====================================================================
// Persistent GRU. Grid = NG*NSL = 56 blocks, 256 threads (4 waves).
// block (g,s): nodes [16g,16g+16), h-cols [64s,64s+64).
// wave w owns cols [64s+16w, 64s+16w+16): its Whh B-frags (3 gates x
// K=512 = 48 frags) live in VGPRs. Wih (K=128) in LDS. Per step:
// poll producer tags -> 32x8B coherent h loads direct to frags ->
// 48 MFMA -> gates -> publish strip (coherent stores + vmcnt ack +
// per-slice tag). x_{t+1} prefetch + its 12 x-part MFMAs run in the
// slack window after publish, before the next poll.
// =====================================================================
__global__ __launch_bounds__(256, 1) void gru_kernel(
    const float* __restrict__ x,     // [TS, NN, FD]
    const float* __restrict__ Wih,   // [G3, FD]
    const float* __restrict__ Whh,   // [G3, HD]
    const float* __restrict__ bih,   // [G3]
    const float* __restrict__ bhh,   // [G3]
    __bf16* __restrict__ h0buf,      // [112, HD] bf16, zero-init (h0)
    __bf16* __restrict__ h1buf,      // [112, HD] bf16
    float*  __restrict__ enc,        // [112, HD] fp32, final h
    int*    __restrict__ bar)        // [NG][16] int tags, zero-init
{
    const int bid = blockIdx.x;
    const int g   = bid >> 3;        // node group 0..6
    const int s   = bid & 7;         // slice 0..7
    const int tid = threadIdx.x;
    const int w   = tid >> 6;        // wave 0..3
    const int ln  = tid & 63;
    const int nb  = g * 16;
    const int mi  = ln & 15;         // node row in frags / gate col low bits
    const int kq8 = (ln >> 4) * 8;   // K sub-offset within 32
    const int cl  = 16 * w + mi;     // col local 0..63
    const int ch  = 64 * s + cl;     // global h col

    __shared__ __align__(16) __bf16 Wx[192][WXST];   // Wih rows [gate][col] x 128
    __shared__ __align__(16) __bf16 Ax[2][16][WXST]; // x_t tiles (ping-pong)
    __shared__ __align__(16) __bf16 Hn[2][16][HNST]; // own h strip (ping-pong)

    // ---- one-time: Wih slice -> LDS ----
    for (int idx = tid; idx < 192 * 32; idx += 256) {
        int row = idx >> 5, c4 = idx & 31;
        int grow = (row >> 6) * HD + 64 * s + (row & 63);
        float4 v = ((const float4*)(Wih + (size_t)grow * FD))[c4];
        __bf16* d = &Wx[row][c4 * 4];
        d[0] = (__bf16)v.x; d[1] = (__bf16)v.y; d[2] = (__bf16)v.z; d[3] = (__bf16)v.w;
    }
    // Hn[0] = 0 (h_0 own strip)
    *(u64*)&Hn[0][tid >> 4][(tid & 15) * 4] = 0ull;

    // ---- one-time: Whh B-frags -> registers (48 frags = 192 VGPRs) ----
    bf16x8 wR[16], wZ[16], wN[16];
    {
        const float* pR = Whh + (size_t)ch * HD;
        const float* pZ = Whh + (size_t)(HD + ch) * HD;
        const float* pN = Whh + (size_t)(2 * HD + ch) * HD;
        #pragma unroll
        for (int kk = 0; kk < 16; ++kk) {
            int ko = 32 * kk + kq8;
            wR[kk] = cvt8(pR + ko);
            wZ[kk] = cvt8(pZ + ko);
            wN[kk] = cvt8(pN + ko);
        }
    }
    const float bR  = bih[ch] + bhh[ch];
    const float bZ  = bih[HD + ch] + bhh[HD + ch];
    const float bNX = bih[2 * HD + ch];
    const float bNH = bhh[2 * HD + ch];

    // x prefetch lane mapping: 16 threads/row, 8 floats each
    const int xrow  = tid >> 4;
    const int xnode = nb + xrow;
    const int xcol  = (tid & 15) * 8;

    // ---- prologue: stage x_0, x-part for t=0 ----
    {
        float4 xa = {0.f, 0.f, 0.f, 0.f}, xb = xa;
        if (xnode < NN) {
            const float* xp = x + (size_t)xnode * FD + xcol;
            xa = ((const float4*)xp)[0];
            xb = ((const float4*)xp)[1];
        }
        bf16x8 v;
        v[0] = (__bf16)xa.x; v[1] = (__bf16)xa.y; v[2] = (__bf16)xa.z; v[3] = (__bf16)xa.w;
        v[4] = (__bf16)xb.x; v[5] = (__bf16)xb.y; v[6] = (__bf16)xb.z; v[7] = (__bf16)xb.w;
        *(bf16x8*)&Ax[0][xrow][xcol] = v;
    }
    __syncthreads();   // Wx, Ax[0], Hn[0] ready

    f32x4 accR = {0.f, 0.f, 0.f, 0.f}, accZ = accR, accNX = accR, accNH = accR;
    #pragma unroll
    for (int kk = 0; kk < 4; ++kk) {
        int ko = 32 * kk + kq8;
        bf16x8 av = *(const bf16x8*)&Ax[0][mi][ko];
        accR  = MFMA16(av, *(const bf16x8*)&Wx[cl][ko],        accR);
        accZ  = MFMA16(av, *(const bf16x8*)&Wx[64 + cl][ko],   accZ);
        accNX = MFMA16(av, *(const bf16x8*)&Wx[128 + cl][ko],  accNX);
    }

    int* tagp = bar + g * 16 + s;

    #pragma unroll 1
    for (int t = 0; t < TS; ++t) {
        const __bf16* hcur = (t & 1) ? h1buf : h0buf;
        __bf16*       hnxt = (t & 1) ? h0buf : h1buf;

        // ---- prefetch x_{t+1} into regs (independent of h) ----
        float4 xa = {0.f, 0.f, 0.f, 0.f}, xb = xa;
        if (t + 1 < TS && xnode < NN) {
            const float* xp = x + ((size_t)(t + 1) * NN + xnode) * FD + xcol;
            xa = ((const float4*)xp)[0];
            xb = ((const float4*)xp)[1];
        }

        // ---- wait for h_t (producer tags >= t) ----
        if (tid == 0) {
            const u64* tp = (const u64*)(bar + g * 16);
            unsigned tt = (unsigned)t;
            for (;;) {
                u64 a = cload(tp), b = cload(tp + 1), c = cload(tp + 2), d = cload(tp + 3);
                if ((unsigned)a >= tt && (unsigned)(a >> 32) >= tt &&
                    (unsigned)b >= tt && (unsigned)(b >> 32) >= tt &&
                    (unsigned)c >= tt && (unsigned)(c >> 32) >= tt &&
                    (unsigned)d >= tt && (unsigned)(d >> 32) >= tt) break;
            }
        }
        __syncthreads();

        // ---- h_t -> frags (coherent 8B loads), 48 MFMA ----
        {
            u64 hq[32];
            const u64* hrow = (const u64*)(hcur + (size_t)(nb + mi) * HD);
            #pragma unroll
            for (int kk = 0; kk < 16; ++kk) {
                int qo = (32 * kk + kq8) >> 2;
                hq[2 * kk]     = cload(hrow + qo);
                hq[2 * kk + 1] = cload(hrow + qo + 1);
            }
            #pragma unroll
            for (int kk = 0; kk < 16; ++kk) {
                HQ q{hq[2 * kk], hq[2 * kk + 1]};
                bf16x8 av = __builtin_bit_cast(bf16x8, q);
                accR  = MFMA16(av, wR[kk], accR);
                accZ  = MFMA16(av, wZ[kk], accZ);
                accNH = MFMA16(av, wN[kk], accNH);
            }
        }

        // ---- gates + h update ----
        const int hslot = t & 1, nslot = (t + 1) & 1;
        #pragma unroll
        for (int e = 0; e < 4; ++e) {
            int row = (ln >> 4) * 4 + e;
            float rv = sigmoidf_(accR[e] + bR);
            float zv = sigmoidf_(accZ[e] + bZ);
            float nv = tanhf_(accNX[e] + bNX + rv * (accNH[e] + bNH));
            float hold = (float)Hn[hslot][row][cl];
            float hnew = (1.f - zv) * nv + zv * hold;
            Hn[nslot][row][cl] = (__bf16)hnew;
            if (t == TS - 1 && nb + row < NN)
                enc[(size_t)(nb + row) * HD + ch] = hnew;
        }
        __syncthreads();   // Hn[nslot] complete

        // ---- publish strip: coherent stores + ack + tag ----
        {
            int srow = tid >> 4, sc4 = (tid & 15) * 4;
            u64 hv = *(const u64*)&Hn[nslot][srow][sc4];
            cstore((u64*)(hnxt + (size_t)(nb + srow) * HD + 64 * s + sc4), hv);
        }
        asm volatile("s_waitcnt vmcnt(0)" ::: "memory");   // strip acked at LLC
        __syncthreads();                                   // all waves acked
        if (tid == 0)
            __hip_atomic_store(tagp, t + 1, __ATOMIC_RELAXED, __HIP_MEMORY_SCOPE_AGENT);

        // ---- stage x_{t+1}, then its x-part MFMAs (slack-window work) ----
        if (t + 1 < TS) {
            bf16x8 v;
            v[0] = (__bf16)xa.x; v[1] = (__bf16)xa.y; v[2] = (__bf16)xa.z; v[3] = (__bf16)xa.w;
            v[4] = (__bf16)xb.x; v[5] = (__bf16)xb.y; v[6] = (__bf16)xb.z; v[7] = (__bf16)xb.w;
            *(bf16x8*)&Ax[nslot][xrow][xcol] = v;
        }
        __syncthreads();   // Ax[nslot] ready

        accR = {0.f, 0.f, 0.f, 0.f}; accZ = accR; accNX = accR; accNH = accR;
        if (t + 1 < TS) {
            #pragma unroll
            for (int kk = 0; kk < 4; ++kk) {
                int ko = 32 * kk + kq8;
                bf16x8 av = *(const bf16x8*)&Ax[nslot][mi][ko];
                accR  = MFMA16(av, *(const bf16x8*)&Wx[cl][ko],       accR);
                accZ  = MFMA16(av, *(const bf16x8*)&Wx[64 + cl][ko],  accZ);
                accNX = MFMA16(av, *(const bf16x8*)&Wx[128 + cl][ko], accNX);
            }
        }
    }
}

// ===================== epilogue (tiny) =====================

__global__ void e1_gnn_in(const float* __restrict__ enc, const float* __restrict__ flat,
                          const float* __restrict__ emb, const float* __restrict__ fW,
                          const float* __restrict__ fb, float* __restrict__ gnn)
{
    int i = blockIdx.x, tid = threadIdx.x;
    const float4* src = (const float4*)(enc + (size_t)i * HD);
    float4* dst = (float4*)(gnn + (size_t)i * GIN);
    dst[tid] = src[tid];
    if (tid < 64) {
        float acc = fb[tid];
        const float* w  = fW + tid * 32;
        const float* fl = flat + i * 32;
        #pragma unroll
        for (int k = 0; k < 32; ++k) acc = fmaf(fl[k], w[k], acc);
        gnn[(size_t)i * GIN + HD + tid] = acc;
    }
    gnn[(size_t)i * GIN + HD + 64 + tid] = emb[(size_t)i * FD + tid];
}

__global__ void e2a_norm(const float* __restrict__ emb, float* __restrict__ mx)
{
    int j = threadIdx.x;
    if (j < NN) {
        float acc = 0.f;
        const float* e = emb + (size_t)j * FD;
        for (int d = 0; d < FD; ++d) acc = fmaf(e[d], e[d], acc);
        mx[j] = fmaxf(sqrtf(acc), 1e-8f);
    }
}

__global__ void e2b_knn(const float* __restrict__ emb, const float* __restrict__ mx,
                        int* __restrict__ tgt)
{
    int i = blockIdx.x, tid = threadIdx.x;   // 128 threads
    __shared__ float ei[FD];
    __shared__ float srow[NN];
    ei[tid] = emb[(size_t)i * FD + tid];
    __syncthreads();
    if (tid < NN) {
        float acc = 0.f;
        const float* e = emb + (size_t)tid * FD;
        for (int d = 0; d < FD; ++d) acc = fmaf(ei[d], e[d], acc);
        float sim = acc / (mx[i] * mx[tid]);
        srow[tid] = (tid == i) ? 0.f : sim;
    }
    __syncthreads();
    if (tid == 0) {
        for (int t = 0; t < KNN; ++t) {
            float best = -1e30f; int bi = 0;
            for (int j = 0; j < NN; ++j) { float v = srow[j]; if (v > best) { best = v; bi = j; } }
            srow[bi] = -1e30f;
            tgt[i * KNN + t] = bi;
        }
    }
}

__global__ void e3_agg(const float* __restrict__ xin, const int* __restrict__ tgt,
                       float* __restrict__ agg, float* __restrict__ cnt, int D)
{
    int e = blockIdx.x, src = e >> 3, tg = tgt[e];
    for (int d = threadIdx.x; d < D; d += blockDim.x)
        atomicAdd(&agg[(size_t)tg * D + d], xin[(size_t)src * D + d]);
    if (threadIdx.x == 0) atomicAdd(&cnt[tg], 1.0f);
}

__global__ void e4_sage(const float* __restrict__ agg, const float* __restrict__ xin,
                        const float* __restrict__ cnt,
                        const float* __restrict__ Wl, const float* __restrict__ Wr,
                        const float* __restrict__ b, float* __restrict__ out,
                        int Din, int Dout, int dorelu)
{
    int j = blockIdx.x, o = threadIdx.x;
    extern __shared__ float sm[];
    float* la = sm;
    float* lx = sm + Din;
    for (int d = o; d < Din; d += blockDim.x) {
        la[d] = agg[(size_t)j * Din + d];
        lx[d] = xin[(size_t)j * Din + d];
    }
    __syncthreads();
    float inv = 1.f / fmaxf(cnt[j], 1.f);
    float acc1 = 0.f, acc2 = 0.f;
    const float* wl = Wl + (size_t)o * Din;
    const float* wr = Wr + (size_t)o * Din;
    for (int k = 0; k < Din; ++k) {
        acc1 = fmaf(la[k], wl[k], acc1);
        acc2 = fmaf(lx[k], wr[k], acc2);
    }
    float v = fmaf(acc1, inv, acc2) + b[o];
    if (dorelu) v = fmaxf(v, 0.f);
    out[(size_t)j * Dout + o] = v;
}

__global__ void e7_out(const float* __restrict__ g, const float* __restrict__ enc,
                       const float* __restrict__ oW, const float* __restrict__ ob,
                       float* __restrict__ out)
{
    int j = threadIdx.x;
    if (j < NN) {
        float acc = ob[0];
        const float* gr = g + (size_t)j * GOUT;
        for (int d = 0; d < GOUT; ++d) acc = fmaf(gr[d], oW[d], acc);
        const float* er = enc + (size_t)j * HD;
        for (int d = 0; d < HD; ++d) acc = fmaf(er[d], oW[GOUT + d], acc);
        out[j] = 1.f / (1.f + expf(-acc));
    }
}

// ===================== launch =====================
extern "C" void kernel_launch(void* const* d_in, const int* in_sizes, int n_in,
                              void* d_out, int out_size, void* d_ws, size_t ws_size,
                              hipStream_t stream)
{
    const float* x    = (const float*)d_in[0];
    const float* flat = (const float*)d_in[1];
    const float* emb  = (const float*)d_in[2];
    const float* Wih  = (const float*)d_in[3];
    const float* Whh  = (const float*)d_in[4];
    const float* bih  = (const float*)d_in[5];
    const float* bhh  = (const float*)d_in[6];
    const float* fW   = (const float*)d_in[7];
    const float* fb   = (const float*)d_in[8];
    const float* s1Wl = (const float*)d_in[9];
    const float* s1Wr = (const float*)d_in[10];
    const float* s1b  = (const float*)d_in[11];
    const float* s2Wl = (const float*)d_in[12];
    const float* s2Wr = (const float*)d_in[13];
    const float* s2b  = (const float*)d_in[14];
    const float* oW   = (const float*)d_in[15];
    const float* ob   = (const float*)d_in[16];
    float* out = (float*)d_out;

    // workspace layout (bytes). Zero zone first -> single memset.
    char* p = (char*)d_ws;
    __bf16* h0buf = (__bf16*)(p + 0);        // 114688  [zero: h0]
    float*  agg1  = (float*)(p + 114688);    // 281600  [zero]
    float*  agg2  = (float*)(p + 396288);    // 102400  [zero]
    float*  cnt1  = (float*)(p + 498688);    // 448     [zero]
    float*  cnt2  = (float*)(p + 499136);    // 448     [zero]
    int*    bar   = (int*)  (p + 499584);    // 1792    [zero: tags]
    __bf16* h1buf = (__bf16*)(p + 501376);   // 114688
    float*  enc   = (float*)(p + 616064);    // 229376
    float*  gnn   = (float*)(p + 845440);    // 281600
    float*  h1s   = (float*)(p + 1127040);   // 102400
    float*  gbuf  = (float*)(p + 1229440);   // 51200
    float*  mx    = (float*)(p + 1280640);   // 448
    int*    tgt   = (int*)  (p + 1281088);   // 3200

    (void)hipMemsetAsync(d_ws, 0, 501376, stream);

    gru_kernel<<<NG * NSL, 256, 0, stream>>>(x, Wih, Whh, bih, bhh, h0buf, h1buf, enc, bar);
    e1_gnn_in<<<NN, 128, 0, stream>>>(enc, flat, emb, fW, fb, gnn);
    e2a_norm<<<1, 128, 0, stream>>>(emb, mx);
    e2b_knn<<<NN, 128, 0, stream>>>(emb, mx, tgt);
    e3_agg<<<NN * KNN, 256, 0, stream>>>(gnn, tgt, agg1, cnt1, GIN);
    e4_sage<<<NN, GH, 2 * GIN * sizeof(float), stream>>>(agg1, gnn, cnt1, s1Wl, s1Wr, s1b, h1s, GIN, GH, 1);
    e3_agg<<<NN * KNN, 256, 0, stream>>>(h1s, tgt, agg2, cnt2, GH);
    e4_sage<<<NN, GOUT, 2 * GH * sizeof(float), stream>>>(agg2, h1s, cnt2, s2Wl, s2Wr, s2b, gbuf, GH, GOUT, 0);
    e7_out<<<1, 128, 0, stream>>>(gbuf, enc, oW, ob, out);
}

// Round 5
// 8504.564 us; speedup vs baseline: 1.5252x; 1.5252x over previous
//
#include <hip/hip_runtime.h>
#include <math.h>

// ---------------- problem constants ----------------
#define TS   2048   // timesteps
#define NN   100    // nodes
#define FD   128    // input features
#define HD   512    // hidden
#define G3   1536   // 3*HD
#define NG   7      // node groups of 16
#define NSL  8      // hidden slices (64 h-cols each)
#define KNN  8
#define GIN  704    // HD + 64 + 128
#define GH   256
#define GOUT 128

typedef float  f32x4  __attribute__((ext_vector_type(4)));
typedef __bf16 bf16x8 __attribute__((ext_vector_type(8)));
#define MFMA16(a, b, c) __builtin_amdgcn_mfma_f32_16x16x32_bf16((a), (b), (c), 0, 0, 0)

#define WXST 136   // Wx/Ax LDS row stride (bf16): 272B, 16B-aligned

__device__ __forceinline__ float sig_(float v) {
    return __builtin_amdgcn_rcpf(1.f + __expf(-v));
}
__device__ __forceinline__ float tanh_(float v) {
    float e = __expf(2.f * v);
    return 1.f - 2.f * __builtin_amdgcn_rcpf(e + 1.f);   // saturates at +/-1
}

// ---------- policy-tagged memory helpers ----------
// sc0       : coherent at the XCD's shared L2 (bypass L1)       [local mode]
// sc0 sc1   : coherent at LLC (bypass L1+L2, cross-XCD safe)    [agent mode]

#define GLD16_BODY(SC) \
        "global_load_dwordx4 %0, %16, %17" SC "\n\t" \
        "global_load_dwordx4 %1, %16, %17 offset:64" SC "\n\t" \
        "global_load_dwordx4 %2, %16, %17 offset:128" SC "\n\t" \
        "global_load_dwordx4 %3, %16, %17 offset:192" SC "\n\t" \
        "global_load_dwordx4 %4, %16, %17 offset:256" SC "\n\t" \
        "global_load_dwordx4 %5, %16, %17 offset:320" SC "\n\t" \
        "global_load_dwordx4 %6, %16, %17 offset:384" SC "\n\t" \
        "global_load_dwordx4 %7, %16, %17 offset:448" SC "\n\t" \
        "global_load_dwordx4 %8, %16, %17 offset:512" SC "\n\t" \
        "global_load_dwordx4 %9, %16, %17 offset:576" SC "\n\t" \
        "global_load_dwordx4 %10, %16, %17 offset:640" SC "\n\t" \
        "global_load_dwordx4 %11, %16, %17 offset:704" SC "\n\t" \
        "global_load_dwordx4 %12, %16, %17 offset:768" SC "\n\t" \
        "global_load_dwordx4 %13, %16, %17 offset:832" SC "\n\t" \
        "global_load_dwordx4 %14, %16, %17 offset:896" SC "\n\t" \
        "global_load_dwordx4 %15, %16, %17 offset:960" SC "\n\t" \
        "s_waitcnt vmcnt(0)"
#define GLD16_ARGS(h, voff, base) \
        : "=&v"(h[0]), "=&v"(h[1]), "=&v"(h[2]), "=&v"(h[3]), \
          "=&v"(h[4]), "=&v"(h[5]), "=&v"(h[6]), "=&v"(h[7]), \
          "=&v"(h[8]), "=&v"(h[9]), "=&v"(h[10]), "=&v"(h[11]), \
          "=&v"(h[12]), "=&v"(h[13]), "=&v"(h[14]), "=&v"(h[15]) \
        : "v"(voff), "s"(base) : "memory"

__device__ __forceinline__ void loadh16_l(const __bf16* base, unsigned voff, f32x4* h) {
    asm volatile(GLD16_BODY(" sc0") GLD16_ARGS(h, voff, base));
}
__device__ __forceinline__ void loadh16_a(const __bf16* base, unsigned voff, f32x4* h) {
    asm volatile(GLD16_BODY(" sc0 sc1") GLD16_ARGS(h, voff, base));
}

#define STH4_BODY(SC) \
        "global_store_short %4, %0, %5" SC "\n\t" \
        "global_store_short %4, %1, %5 offset:1024" SC "\n\t" \
        "global_store_short %4, %2, %5 offset:2048" SC "\n\t" \
        "global_store_short %4, %3, %5 offset:3072" SC
__device__ __forceinline__ void storeh4_l(__bf16* base, unsigned voff,
                                          unsigned v0, unsigned v1, unsigned v2, unsigned v3) {
    asm volatile(STH4_BODY(" sc0")
                 :: "v"(v0), "v"(v1), "v"(v2), "v"(v3), "v"(voff), "s"(base) : "memory");
}
__device__ __forceinline__ void storeh4_a(__bf16* base, unsigned voff,
                                          unsigned v0, unsigned v1, unsigned v2, unsigned v3) {
    asm volatile(STH4_BODY(" sc0 sc1")
                 :: "v"(v0), "v"(v1), "v"(v2), "v"(v3), "v"(voff), "s"(base) : "memory");
}

__device__ __forceinline__ void tagstore_l(int* base, unsigned voff, int val) {
    asm volatile("global_store_dword %1, %0, %2 sc0" :: "v"(val), "v"(voff), "s"(base) : "memory");
}
__device__ __forceinline__ void tagstore_a(int* base, unsigned voff, int val) {
    asm volatile("global_store_dword %1, %0, %2 sc0 sc1" :: "v"(val), "v"(voff), "s"(base) : "memory");
}
__device__ __forceinline__ int tagload_l(const int* base, unsigned voff) {
    int v;
    asm volatile("global_load_dword %0, %1, %2 sc0\n\ts_waitcnt vmcnt(0)"
                 : "=v"(v) : "v"(voff), "s"(base) : "memory");
    return v;
}
__device__ __forceinline__ int tagload_a(const int* base, unsigned voff) {
    int v;
    asm volatile("global_load_dword %0, %1, %2 sc0 sc1\n\ts_waitcnt vmcnt(0)"
                 : "=v"(v) : "v"(voff), "s"(base) : "memory");
    return v;
}

__device__ __forceinline__ bf16x8 cvt8(const float* p) {
    float4 a = *(const float4*)p, b = *(const float4*)(p + 4);
    bf16x8 r;
    r[0] = (__bf16)a.x; r[1] = (__bf16)a.y; r[2] = (__bf16)a.z; r[3] = (__bf16)a.w;
    r[4] = (__bf16)b.x; r[5] = (__bf16)b.y; r[6] = (__bf16)b.z; r[7] = (__bf16)b.w;
    return r;
}

// =====================================================================
// Persistent GRU main loop. 56 blocks x 256 threads (4 waves).
// block (g,s): nodes [16g,16g+16), h-cols [64s,64s+64); wave w: 16 cols.
// Whh B-frags (48 = 192 regs) in registers; Wih in LDS; hold in regs.
// LOCAL=true: group's 8 blocks share one XCD -> h/tags via sc0 (L2).
// LOCAL=false: agent path via sc0 sc1 (LLC) -- placement-independent.
// =====================================================================
template<bool LOCAL>
__device__ void gru_loop(const float* __restrict__ x,
                         const float* __restrict__ Wih, const float* __restrict__ Whh,
                         const float* __restrict__ bih, const float* __restrict__ bhh,
                         __bf16* h0buf, __bf16* h1buf, float* enc, int* tags,
                         int g, int s, __bf16* WxP, __bf16* AxP)
{
    const int tid = threadIdx.x;
    const int w   = tid >> 6;
    const int ln  = tid & 63;
    const int nb  = g * 16;
    const int mi  = ln & 15;
    const int kq8 = (ln >> 4) * 8;
    const int cl  = 16 * w + mi;
    const int ch  = 64 * s + cl;

    // ---- one-time: Wih slice -> LDS (192 gate rows x 128 K) ----
    for (int idx = tid; idx < 192 * 32; idx += 256) {
        int row = idx >> 5, c4 = idx & 31;
        int grow = (row >> 6) * HD + 64 * s + (row & 63);
        float4 v = ((const float4*)(Wih + (size_t)grow * FD))[c4];
        __bf16* d = WxP + row * WXST + c4 * 4;
        d[0] = (__bf16)v.x; d[1] = (__bf16)v.y; d[2] = (__bf16)v.z; d[3] = (__bf16)v.w;
    }

    // ---- one-time: Whh B-frags -> registers ----
    bf16x8 wR[16], wZ[16], wN[16];
    {
        const float* pR = Whh + (size_t)ch * HD;
        const float* pZ = Whh + (size_t)(HD + ch) * HD;
        const float* pN = Whh + (size_t)(2 * HD + ch) * HD;
        #pragma unroll
        for (int kk = 0; kk < 16; ++kk) {
            int ko = 32 * kk + kq8;
            wR[kk] = cvt8(pR + ko);
            wZ[kk] = cvt8(pZ + ko);
            wN[kk] = cvt8(pN + ko);
        }
    }
    const float bR  = bih[ch] + bhh[ch];
    const float bZ  = bih[HD + ch] + bhh[HD + ch];
    const float bNX = bih[2 * HD + ch];
    const float bNH = bhh[2 * HD + ch];

    const int xrow  = tid >> 4;
    const int xnode = nb + xrow;
    const int xcol  = (tid & 15) * 8;

    // ---- prologue: stage x_0, x-part MFMAs for t=0 ----
    {
        float4 xa = {0.f, 0.f, 0.f, 0.f}, xb = xa;
        if (xnode < NN) {
            const float* xp = x + (size_t)xnode * FD + xcol;
            xa = ((const float4*)xp)[0];
            xb = ((const float4*)xp)[1];
        }
        bf16x8 v;
        v[0] = (__bf16)xa.x; v[1] = (__bf16)xa.y; v[2] = (__bf16)xa.z; v[3] = (__bf16)xa.w;
        v[4] = (__bf16)xb.x; v[5] = (__bf16)xb.y; v[6] = (__bf16)xb.z; v[7] = (__bf16)xb.w;
        *(bf16x8*)(AxP + (size_t)xrow * WXST + xcol) = v;
    }
    __syncthreads();

    f32x4 accR = {0.f, 0.f, 0.f, 0.f}, accZ = accR, accNX = accR, accNH = accR;
    #pragma unroll
    for (int kk = 0; kk < 4; ++kk) {
        int ko = 32 * kk + kq8;
        bf16x8 av = *(const bf16x8*)(AxP + (size_t)mi * WXST + ko);
        accR  = MFMA16(av, *(const bf16x8*)(WxP + (size_t)cl * WXST + ko),         accR);
        accZ  = MFMA16(av, *(const bf16x8*)(WxP + (size_t)(64 + cl) * WXST + ko),  accZ);
        accNX = MFMA16(av, *(const bf16x8*)(WxP + (size_t)(128 + cl) * WXST + ko), accNX);
    }

    float hold[4] = {0.f, 0.f, 0.f, 0.f};

    const unsigned hv_voff = ((unsigned)(nb + mi) * HD + (unsigned)kq8) * 2u;
    const unsigned st_voff = ((unsigned)(nb + (ln >> 4) * 4) * HD + (unsigned)ch) * 2u;
    const unsigned tg_self = (unsigned)(g * NSL + s) * 64u;
    const unsigned tg_poll = (unsigned)(g * NSL + (ln & 7)) * 64u;

    #pragma unroll 1
    for (int t = 0; t < TS; ++t) {
        __bf16* hcur = (t & 1) ? h1buf : h0buf;
        __bf16* hnxt = (t & 1) ? h0buf : h1buf;

        // ---- prefetch x_{t+1} (plain cached loads; overlaps poll) ----
        float4 xa = {0.f, 0.f, 0.f, 0.f}, xb = xa;
        if (t + 1 < TS && xnode < NN) {
            const float* xp = x + ((size_t)(t + 1) * NN + xnode) * FD + xcol;
            xa = ((const float4*)xp)[0];
            xb = ((const float4*)xp)[1];
        }

        // ---- wait for h_t: every wave polls all 8 tags in parallel ----
        for (;;) {
            int v = LOCAL ? tagload_l(tags, tg_poll) : tagload_a(tags, tg_poll);
            if (__all((ln < 8) ? (v >= t) : 1)) break;
        }

        // ---- h_t -> 16 frags (one bundled load, policy-routed) ----
        f32x4 hv[16];
        if (LOCAL) loadh16_l(hcur, hv_voff, hv);
        else       loadh16_a(hcur, hv_voff, hv);

        #pragma unroll
        for (int kk = 0; kk < 16; ++kk) {
            bf16x8 av = __builtin_bit_cast(bf16x8, hv[kk]);
            accR  = MFMA16(av, wR[kk], accR);
            accZ  = MFMA16(av, wZ[kk], accZ);
            accNH = MFMA16(av, wN[kk], accNH);
        }

        // ---- gates + h update (hold in regs) + direct publish ----
        unsigned pv[4];
        #pragma unroll
        for (int e = 0; e < 4; ++e) {
            float rv = sig_(accR[e] + bR);
            float zv = sig_(accZ[e] + bZ);
            float nv = tanh_(accNX[e] + bNX + rv * (accNH[e] + bNH));
            float hnew = (1.f - zv) * nv + zv * hold[e];
            hold[e] = hnew;
            pv[e] = (unsigned)__builtin_bit_cast(unsigned short, (__bf16)hnew);
        }
        if (LOCAL) storeh4_l(hnxt, st_voff, pv[0], pv[1], pv[2], pv[3]);
        else       storeh4_a(hnxt, st_voff, pv[0], pv[1], pv[2], pv[3]);
        asm volatile("s_waitcnt vmcnt(0)" ::: "memory");   // strip acked at coherence point
        __syncthreads();                                   // all waves acked
        if (tid == 0) {
            if (LOCAL) tagstore_l(tags, tg_self, t + 1);
            else       tagstore_a(tags, tg_self, t + 1);
        }

        // ---- slack window: stage x_{t+1}, run its x-part MFMAs ----
        const int nslot = (t + 1) & 1;
        if (t + 1 < TS) {
            bf16x8 v;
            v[0] = (__bf16)xa.x; v[1] = (__bf16)xa.y; v[2] = (__bf16)xa.z; v[3] = (__bf16)xa.w;
            v[4] = (__bf16)xb.x; v[5] = (__bf16)xb.y; v[6] = (__bf16)xb.z; v[7] = (__bf16)xb.w;
            *(bf16x8*)(AxP + ((size_t)nslot * 16 + xrow) * WXST + xcol) = v;
        }
        __syncthreads();

        accR = {0.f, 0.f, 0.f, 0.f}; accZ = accR; accNX = accR; accNH = accR;
        if (t + 1 < TS) {
            #pragma unroll
            for (int kk = 0; kk < 4; ++kk) {
                int ko = 32 * kk + kq8;
                bf16x8 av = *(const bf16x8*)(AxP + ((size_t)nslot * 16 + mi) * WXST + ko);
                accR  = MFMA16(av, *(const bf16x8*)(WxP + (size_t)cl * WXST + ko),         accR);
                accZ  = MFMA16(av, *(const bf16x8*)(WxP + (size_t)(64 + cl) * WXST + ko),  accZ);
                accNX = MFMA16(av, *(const bf16x8*)(WxP + (size_t)(128 + cl) * WXST + ko), accNX);
            }
        }
    }

    // ---- epilogue: final h -> enc (fp32) ----
    #pragma unroll
    for (int e = 0; e < 4; ++e) {
        int row = (ln >> 4) * 4 + e;
        if (nb + row < NN)
            enc[(size_t)(nb + row) * HD + ch] = hold[e];
    }
}

// sync layout (ints): [0..895] tags (64B-padded per slot), [896..] claim,
// [960..] slot-xcc table, [1024] rendezvous counter. All zero-initialized.
__global__ __launch_bounds__(256, 1) void gru_kernel(
    const float* __restrict__ x, const float* __restrict__ Wih,
    const float* __restrict__ Whh, const float* __restrict__ bih,
    const float* __restrict__ bhh,
    __bf16* h0buf, __bf16* h1buf, float* enc, int* sync)
{
    __shared__ int sh_slot, sh_loc;
    __shared__ __align__(16) __bf16 Wx[192 * WXST];
    __shared__ __align__(16) __bf16 Ax[2 * 16 * WXST];

    int* tags  = sync;
    int* claim = sync + 896;
    int* sxcc  = sync + 960;
    int* ready = sync + 1024;

    // ---- placement-aware slot claim (one-time, correctness-robust) ----
    if (threadIdx.x == 0) {
        int xcc = 0;
        asm volatile("s_getreg_b32 %0, hwreg(HW_REG_XCC_ID)" : "=s"(xcc));
        int slot = -1;
        if (xcc < NG) {                       // prefer group == own XCD
            for (int k = xcc * NSL; k < xcc * NSL + NSL && slot < 0; ++k) {
                int e0 = 0;
                if (__hip_atomic_compare_exchange_strong(claim + k, &e0, 1,
                        __ATOMIC_RELAXED, __ATOMIC_RELAXED, __HIP_MEMORY_SCOPE_AGENT))
                    slot = k;
            }
        }
        for (int k = 0; k < NG * NSL && slot < 0; ++k) {   // leftover sweep
            int e0 = 0;
            if (__hip_atomic_compare_exchange_strong(claim + k, &e0, 1,
                    __ATOMIC_RELAXED, __ATOMIC_RELAXED, __HIP_MEMORY_SCOPE_AGENT))
                slot = k;
        }
        __hip_atomic_store(sxcc + slot, xcc + 1, __ATOMIC_RELAXED, __HIP_MEMORY_SCOPE_AGENT);
        __hip_atomic_fetch_add(ready, 1, __ATOMIC_RELAXED, __HIP_MEMORY_SCOPE_AGENT);
        while (__hip_atomic_load(ready, __ATOMIC_RELAXED, __HIP_MEMORY_SCOPE_AGENT) < NG * NSL)
            __builtin_amdgcn_s_sleep(8);
        int base = (slot / NSL) * NSL;
        int x0 = __hip_atomic_load(sxcc + base, __ATOMIC_RELAXED, __HIP_MEMORY_SCOPE_AGENT);
        int loc = 1;
        for (int k = 1; k < NSL; ++k)
            loc &= (__hip_atomic_load(sxcc + base + k, __ATOMIC_RELAXED,
                                      __HIP_MEMORY_SCOPE_AGENT) == x0);
        sh_slot = slot; sh_loc = loc;
    }
    __syncthreads();
    const int slot = sh_slot;
    const int g = slot / NSL, s = slot % NSL;

    if (sh_loc) gru_loop<true >(x, Wih, Whh, bih, bhh, h0buf, h1buf, enc, tags, g, s, Wx, Ax);
    else        gru_loop<false>(x, Wih, Whh, bih, bhh, h0buf, h1buf, enc, tags, g, s, Wx, Ax);
}

// ===================== epilogue (tiny) =====================

__global__ void e1_gnn_in(const float* __restrict__ enc, const float* __restrict__ flat,
                          const float* __restrict__ emb, const float* __restrict__ fW,
                          const float* __restrict__ fb, float* __restrict__ gnn)
{
    int i = blockIdx.x, tid = threadIdx.x;
    const float4* src = (const float4*)(enc + (size_t)i * HD);
    float4* dst = (float4*)(gnn + (size_t)i * GIN);
    dst[tid] = src[tid];
    if (tid < 64) {
        float acc = fb[tid];
        const float* w  = fW + tid * 32;
        const float* fl = flat + i * 32;
        #pragma unroll
        for (int k = 0; k < 32; ++k) acc = fmaf(fl[k], w[k], acc);
        gnn[(size_t)i * GIN + HD + tid] = acc;
    }
    gnn[(size_t)i * GIN + HD + 64 + tid] = emb[(size_t)i * FD + tid];
}

__global__ void e2a_norm(const float* __restrict__ emb, float* __restrict__ mx)
{
    int j = threadIdx.x;
    if (j < NN) {
        float acc = 0.f;
        const float* e = emb + (size_t)j * FD;
        for (int d = 0; d < FD; ++d) acc = fmaf(e[d], e[d], acc);
        mx[j] = fmaxf(sqrtf(acc), 1e-8f);
    }
}

__global__ void e2b_knn(const float* __restrict__ emb, const float* __restrict__ mx,
                        int* __restrict__ tgt)
{
    int i = blockIdx.x, tid = threadIdx.x;   // 128 threads
    __shared__ float ei[FD];
    __shared__ float srow[NN];
    ei[tid] = emb[(size_t)i * FD + tid];
    __syncthreads();
    if (tid < NN) {
        float acc = 0.f;
        const float* e = emb + (size_t)tid * FD;
        for (int d = 0; d < FD; ++d) acc = fmaf(ei[d], e[d], acc);
        float sim = acc / (mx[i] * mx[tid]);
        srow[tid] = (tid == i) ? 0.f : sim;
    }
    __syncthreads();
    if (tid == 0) {
        for (int t = 0; t < KNN; ++t) {
            float best = -1e30f; int bi = 0;
            for (int j = 0; j < NN; ++j) { float v = srow[j]; if (v > best) { best = v; bi = j; } }
            srow[bi] = -1e30f;
            tgt[i * KNN + t] = bi;
        }
    }
}

__global__ void e3_agg(const float* __restrict__ xin, const int* __restrict__ tgt,
                       float* __restrict__ agg, float* __restrict__ cnt, int D)
{
    int e = blockIdx.x, src = e >> 3, tg = tgt[e];
    for (int d = threadIdx.x; d < D; d += blockDim.x)
        atomicAdd(&agg[(size_t)tg * D + d], xin[(size_t)src * D + d]);
    if (threadIdx.x == 0) atomicAdd(&cnt[tg], 1.0f);
}

__global__ void e4_sage(const float* __restrict__ agg, const float* __restrict__ xin,
                        const float* __restrict__ cnt,
                        const float* __restrict__ Wl, const float* __restrict__ Wr,
                        const float* __restrict__ b, float* __restrict__ out,
                        int Din, int Dout, int dorelu)
{
    int j = blockIdx.x, o = threadIdx.x;
    extern __shared__ float sm[];
    float* la = sm;
    float* lx = sm + Din;
    for (int d = o; d < Din; d += blockDim.x) {
        la[d] = agg[(size_t)j * Din + d];
        lx[d] = xin[(size_t)j * Din + d];
    }
    __syncthreads();
    float inv = 1.f / fmaxf(cnt[j], 1.f);
    float acc1 = 0.f, acc2 = 0.f;
    const float* wl = Wl + (size_t)o * Din;
    const float* wr = Wr + (size_t)o * Din;
    for (int k = 0; k < Din; ++k) {
        acc1 = fmaf(la[k], wl[k], acc1);
        acc2 = fmaf(lx[k], wr[k], acc2);
    }
    float v = fmaf(acc1, inv, acc2) + b[o];
    if (dorelu) v = fmaxf(v, 0.f);
    out[(size_t)j * Dout + o] = v;
}

__global__ void e7_out(const float* __restrict__ g, const float* __restrict__ enc,
                       const float* __restrict__ oW, const float* __restrict__ ob,
                       float* __restrict__ out)
{
    int j = threadIdx.x;
    if (j < NN) {
        float acc = ob[0];
        const float* gr = g + (size_t)j * GOUT;
        for (int d = 0; d < GOUT; ++d) acc = fmaf(gr[d], oW[d], acc);
        const float* er = enc + (size_t)j * HD;
        for (int d = 0; d < HD; ++d) acc = fmaf(er[d], oW[GOUT + d], acc);
        out[j] = 1.f / (1.f + expf(-acc));
    }
}

// ===================== launch =====================
extern "C" void kernel_launch(void* const* d_in, const int* in_sizes, int n_in,
                              void* d_out, int out_size, void* d_ws, size_t ws_size,
                              hipStream_t stream)
{
    const float* x    = (const float*)d_in[0];
    const float* flat = (const float*)d_in[1];
    const float* emb  = (const float*)d_in[2];
    const float* Wih  = (const float*)d_in[3];
    const float* Whh  = (const float*)d_in[4];
    const float* bih  = (const float*)d_in[5];
    const float* bhh  = (const float*)d_in[6];
    const float* fW   = (const float*)d_in[7];
    const float* fb   = (const float*)d_in[8];
    const float* s1Wl = (const float*)d_in[9];
    const float* s1Wr = (const float*)d_in[10];
    const float* s1b  = (const float*)d_in[11];
    const float* s2Wl = (const float*)d_in[12];
    const float* s2Wr = (const float*)d_in[13];
    const float* s2b  = (const float*)d_in[14];
    const float* oW   = (const float*)d_in[15];
    const float* ob   = (const float*)d_in[16];
    float* out = (float*)d_out;

    // workspace layout (bytes). Zero zone first -> single memset.
    char* p = (char*)d_ws;
    __bf16* h0buf = (__bf16*)(p + 0);        // 114688  [zero: h0]
    float*  agg1  = (float*)(p + 114688);    // 281600  [zero]
    float*  agg2  = (float*)(p + 396288);    // 102400  [zero]
    float*  cnt1  = (float*)(p + 498688);    // 448     [zero]
    float*  cnt2  = (float*)(p + 499136);    // 448     [zero]
    int*    sync  = (int*)  (p + 499584);    // 4608    [zero: tags/claim/rendezvous]
    __bf16* h1buf = (__bf16*)(p + 504192);   // 114688
    float*  enc   = (float*)(p + 618880);    // 229376
    float*  gnn   = (float*)(p + 848256);    // 281600
    float*  h1s   = (float*)(p + 1129856);   // 102400
    float*  gbuf  = (float*)(p + 1232256);   // 51200
    float*  mx    = (float*)(p + 1283456);   // 448
    int*    tgt   = (int*)  (p + 1283904);   // 3200
    // total ~1.29 MiB

    (void)hipMemsetAsync(d_ws, 0, 504192, stream);

    gru_kernel<<<NG * NSL, 256, 0, stream>>>(x, Wih, Whh, bih, bhh, h0buf, h1buf, enc, sync);
    e1_gnn_in<<<NN, 128, 0, stream>>>(enc, flat, emb, fW, fb, gnn);
    e2a_norm<<<1, 128, 0, stream>>>(emb, mx);
    e2b_knn<<<NN, 128, 0, stream>>>(emb, mx, tgt);
    e3_agg<<<NN * KNN, 256, 0, stream>>>(gnn, tgt, agg1, cnt1, GIN);
    e4_sage<<<NN, GH, 2 * GIN * sizeof(float), stream>>>(agg1, gnn, cnt1, s1Wl, s1Wr, s1b, h1s, GIN, GH, 1);
    e3_agg<<<NN * KNN, 256, 0, stream>>>(h1s, tgt, agg2, cnt2, GH);
    e4_sage<<<NN, GOUT, 2 * GH * sizeof(float), stream>>>(agg2, h1s, cnt2, s2Wl, s2Wr, s2b, gbuf, GH, GOUT, 0);
    e7_out<<<1, 128, 0, stream>>>(gbuf, enc, oW, ob, out);
}